// Round 1
// baseline (1073.327 us; speedup 1.0000x reference)
//
#include <hip/hip_runtime.h>

#define DEV __device__ __forceinline__

typedef __attribute__((ext_vector_type(8))) short short8;
typedef __attribute__((ext_vector_type(4))) float floatx4;

constexpr int Tn  = 4096;   // tokens (B*S)
constexpr int Dm  = 2048;   // model dim
constexpr int In  = 1408;   // expert inter dim
constexpr int En  = 8;      // experts
constexpr int SIn = 2816;   // shared inter dim (2*1408)
constexpr int CAP = 9216;   // 8192 pairs + 8*128 padding

DEV unsigned short f2bf(float f) {          // fp32 -> bf16 RNE
  unsigned int u = __float_as_uint(f);
  u += 0x7FFF + ((u >> 16) & 1);
  return (unsigned short)(u >> 16);
}

DEV void gl2lds16(const unsigned short* g, unsigned short* l) {
  // async global->LDS, 16B/lane; LDS dst = uniform base + lane*16
  __builtin_amdgcn_global_load_lds(
      (const __attribute__((address_space(1))) unsigned int*)g,
      (__attribute__((address_space(3))) unsigned int*)l, 16, 0, 0);
}

// ---------------- conversion kernels ----------------

__global__ void convert_kernel(const float* __restrict__ src,
                               unsigned short* __restrict__ dst, int n4) {
  int i = blockIdx.x * 256 + threadIdx.x;
  if (i >= n4) return;
  float4 v = ((const float4*)src)[i];
  union { unsigned short u[4]; unsigned long long ll; } p;
  p.u[0] = f2bf(v.x); p.u[1] = f2bf(v.y); p.u[2] = f2bf(v.z); p.u[3] = f2bf(v.w);
  *(unsigned long long*)(dst + (long)i * 4) = p.ll;
}

// src [E][R][C] fp32 -> dst [E][C][R] bf16 (transpose per expert)
__global__ void transpose_convert_kernel(const float* __restrict__ src,
                                         unsigned short* __restrict__ dst,
                                         int R, int C) {
  __shared__ float tile[32][33];
  int tilesC = C >> 5;
  int tr = (blockIdx.x / tilesC) << 5;
  int tc = (blockIdx.x % tilesC) << 5;
  const float* s = src + (long)blockIdx.y * R * C;
  unsigned short* d = dst + (long)blockIdx.y * R * C;
  int tx = threadIdx.x & 31, ty = threadIdx.x >> 5;   // 32 x 8
#pragma unroll
  for (int i = 0; i < 4; i++)
    tile[ty + 8 * i][tx] = s[(long)(tr + ty + 8 * i) * C + tc + tx];
  __syncthreads();
#pragma unroll
  for (int i = 0; i < 4; i++)
    d[(long)(tc + ty + 8 * i) * R + tr + tx] = f2bf(tile[tx][ty + 8 * i]);
}

// ---------------- routing ----------------

__global__ void init_counts_kernel(int* counts) {
  if (threadIdx.x < En) counts[threadIdx.x] = 0;
}

// one wave per token; fp64 scores so top-k matches the numpy reference
__global__ void router_kernel(const float* __restrict__ X, const float* __restrict__ GW,
                              const float* __restrict__ bias,
                              int* __restrict__ route_e, float* __restrict__ route_w,
                              int* __restrict__ counts) {
  int t = blockIdx.x, lane = threadIdx.x;
  const float* xr = X + (long)t * Dm;
  double acc[En];
#pragma unroll
  for (int e = 0; e < En; e++) acc[e] = 0.0;
  for (int d = lane; d < Dm; d += 64) {
    double xv = (double)xr[d];
#pragma unroll
    for (int e = 0; e < En; e++) acc[e] += xv * (double)GW[e * Dm + d];
  }
#pragma unroll
  for (int off = 32; off > 0; off >>= 1) {
#pragma unroll
    for (int e = 0; e < En; e++) acc[e] += __shfl_down(acc[e], off);
  }
  if (lane == 0) {
    double sc[En], sel[En];
#pragma unroll
    for (int e = 0; e < En; e++) {
      sc[e] = 1.0 / (1.0 + exp(-acc[e]));
      sel[e] = sc[e] + (double)bias[e];
    }
    int i0 = 0;
#pragma unroll
    for (int e = 1; e < En; e++) if (sel[e] > sel[i0]) i0 = e;
    int i1 = (i0 == 0) ? 1 : 0;
#pragma unroll
    for (int e = 0; e < En; e++) if (e != i0 && sel[e] > sel[i1]) i1 = e;
    double s = sc[i0] + sc[i1];
    if (s < 1e-12) s = 1e-12;
    route_e[t * 2] = i0;  route_e[t * 2 + 1] = i1;
    route_w[t * 2] = (float)(sc[i0] / s);  route_w[t * 2 + 1] = (float)(sc[i1] / s);
    atomicAdd(&counts[i0], 1);  atomicAdd(&counts[i1], 1);
  }
}

__global__ void offsets_kernel(const int* __restrict__ counts,
                               int* __restrict__ offs, int* __restrict__ fill) {
  if (threadIdx.x == 0) {
    int off = 0;
    for (int e = 0; e < En; e++) {
      offs[e] = off; fill[e] = off;
      off += (counts[e] + 127) & ~127;      // pad each expert segment to 128
    }
    offs[En] = off;
  }
}

__global__ void init_pairs_kernel(int* pt, float* pw) {
  int i = blockIdx.x * 256 + threadIdx.x;
  if (i < CAP) { pt[i] = 0; pw[i] = 0.0f; }   // pads: token 0, weight 0
}

__global__ void scatter_kernel(const int* __restrict__ re, const float* __restrict__ rw,
                               int* __restrict__ fill, int* __restrict__ pt,
                               float* __restrict__ pw) {
  int i = blockIdx.x * 256 + threadIdx.x;
  if (i < Tn * 2) {
    int e = re[i];
    int slot = atomicAdd(&fill[e], 1);
    pt[slot] = i >> 1;
    pw[slot] = rw[i];
  }
}

// ---------------- GEMM stage 1: h = silu(A@W1) * (A@W3) ----------------
// A rows gathered via pair_token (routed) or identity (shared).
// B1/B3 are B^T layout [N][K] bf16. Output act [rows][N] bf16.

template<bool GATHER>
__global__ __launch_bounds__(256, 2)
void h_gemm_kernel(const unsigned short* __restrict__ A,
                   const unsigned short* __restrict__ B1b,
                   const unsigned short* __restrict__ B3b,
                   unsigned short* __restrict__ act,
                   const int* __restrict__ pair_token,
                   const int* __restrict__ offs,
                   int N, long estride) {
  __shared__ unsigned short sA[128 * 64];
  __shared__ unsigned short sB1[128 * 64];
  __shared__ unsigned short sB3[128 * 64];
  const int Kd = Dm;
  int m0 = blockIdx.x * 128, n0 = blockIdx.y * 128;
  const unsigned short* B1p = B1b;
  const unsigned short* B3p = B3b;
  if (GATHER) {
    if (m0 >= offs[En]) return;                    // beyond padded total
    int e = 0;
    while (!(m0 >= offs[e] && m0 < offs[e + 1])) e++;
    B1p += (long)e * estride;
    B3p += (long)e * estride;
  }
  int tid = threadIdx.x, wave = tid >> 6, lane = tid & 63;
  int lr = lane >> 3, lc = lane & 7;
  const unsigned short *gA[4], *gB1[4], *gB3[4];
#pragma unroll
  for (int j = 0; j < 4; j++) {
    int r = wave * 32 + j * 8 + lr;
    long arow = GATHER ? (long)pair_token[m0 + r] : (long)(m0 + r);
    gA[j]  = A   + arow * Kd + lc * 8;
    gB1[j] = B1p + (long)(n0 + r) * Kd + lc * 8;
    gB3[j] = B3p + (long)(n0 + r) * Kd + lc * 8;
  }
  int wm = wave >> 1, wn = wave & 1;
  int fr = lane & 15, fq = lane >> 4;
  floatx4 acc1[4][4], acc3[4][4];
#pragma unroll
  for (int mi = 0; mi < 4; mi++)
#pragma unroll
    for (int ni = 0; ni < 4; ni++) { acc1[mi][ni] = (floatx4)0.0f; acc3[mi][ni] = (floatx4)0.0f; }

  for (int k0 = 0; k0 < Kd; k0 += 64) {
    __syncthreads();
#pragma unroll
    for (int j = 0; j < 4; j++) {
      int rb = (wave * 32 + j * 8) * 64;
      gl2lds16(gA[j]  + k0, &sA[rb]);
      gl2lds16(gB1[j] + k0, &sB1[rb]);
      gl2lds16(gB3[j] + k0, &sB3[rb]);
    }
    __syncthreads();
#pragma unroll
    for (int kk = 0; kk < 2; kk++) {
      short8 af[4], b1f[4], b3f[4];
#pragma unroll
      for (int i = 0; i < 4; i++) {
        af[i]  = *(const short8*)&sA [(wm * 64 + i * 16 + fr) * 64 + kk * 32 + fq * 8];
        b1f[i] = *(const short8*)&sB1[(wn * 64 + i * 16 + fr) * 64 + kk * 32 + fq * 8];
        b3f[i] = *(const short8*)&sB3[(wn * 64 + i * 16 + fr) * 64 + kk * 32 + fq * 8];
      }
#pragma unroll
      for (int mi = 0; mi < 4; mi++)
#pragma unroll
        for (int ni = 0; ni < 4; ni++) {
          acc1[mi][ni] = __builtin_amdgcn_mfma_f32_16x16x32_bf16(af[mi], b1f[ni], acc1[mi][ni], 0, 0, 0);
          acc3[mi][ni] = __builtin_amdgcn_mfma_f32_16x16x32_bf16(af[mi], b3f[ni], acc3[mi][ni], 0, 0, 0);
        }
    }
  }
  // epilogue: act = bf16( silu(h1) * h3 );  C/D layout: col=lane&15, row=(lane>>4)*4+reg
#pragma unroll
  for (int mi = 0; mi < 4; mi++)
#pragma unroll
    for (int ni = 0; ni < 4; ni++)
#pragma unroll
      for (int r = 0; r < 4; r++) {
        int row = m0 + wm * 64 + mi * 16 + fq * 4 + r;
        int col = n0 + wn * 64 + ni * 16 + fr;
        float h1 = acc1[mi][ni][r], h3 = acc3[mi][ni][r];
        float v = h1 / (1.0f + __expf(-h1)) * h3;
        act[(long)row * N + col] = f2bf(v);
      }
}

// ---------------- GEMM stage 2: out = act @ W2 ----------------
// SCATTER: out[token] += w * C (atomic).  else: plain store (covers all of d_out).

template<bool SCATTER>
__global__ __launch_bounds__(256, 2)
void o_gemm_kernel(const unsigned short* __restrict__ A,
                   const unsigned short* __restrict__ Bb,
                   float* __restrict__ out,
                   const int* __restrict__ pair_token,
                   const float* __restrict__ pair_w,
                   const int* __restrict__ offs,
                   int Kd, long estride) {
  __shared__ unsigned short sA[128 * 64];
  __shared__ unsigned short sB[128 * 64];
  int m0 = blockIdx.x * 128, n0 = blockIdx.y * 128;
  const unsigned short* Bp = Bb;
  if (SCATTER) {
    if (m0 >= offs[En]) return;
    int e = 0;
    while (!(m0 >= offs[e] && m0 < offs[e + 1])) e++;
    Bp += (long)e * estride;
  }
  int tid = threadIdx.x, wave = tid >> 6, lane = tid & 63;
  int lr = lane >> 3, lc = lane & 7;
  const unsigned short *gA[4], *gB[4];
#pragma unroll
  for (int j = 0; j < 4; j++) {
    int r = wave * 32 + j * 8 + lr;
    gA[j] = A  + (long)(m0 + r) * Kd + lc * 8;
    gB[j] = Bp + (long)(n0 + r) * Kd + lc * 8;
  }
  int wm = wave >> 1, wn = wave & 1;
  int fr = lane & 15, fq = lane >> 4;
  floatx4 acc[4][4];
#pragma unroll
  for (int mi = 0; mi < 4; mi++)
#pragma unroll
    for (int ni = 0; ni < 4; ni++) acc[mi][ni] = (floatx4)0.0f;

  for (int k0 = 0; k0 < Kd; k0 += 64) {
    __syncthreads();
#pragma unroll
    for (int j = 0; j < 4; j++) {
      int rb = (wave * 32 + j * 8) * 64;
      gl2lds16(gA[j] + k0, &sA[rb]);
      gl2lds16(gB[j] + k0, &sB[rb]);
    }
    __syncthreads();
#pragma unroll
    for (int kk = 0; kk < 2; kk++) {
      short8 af[4], bf[4];
#pragma unroll
      for (int i = 0; i < 4; i++) {
        af[i] = *(const short8*)&sA[(wm * 64 + i * 16 + fr) * 64 + kk * 32 + fq * 8];
        bf[i] = *(const short8*)&sB[(wn * 64 + i * 16 + fr) * 64 + kk * 32 + fq * 8];
      }
#pragma unroll
      for (int mi = 0; mi < 4; mi++)
#pragma unroll
        for (int ni = 0; ni < 4; ni++)
          acc[mi][ni] = __builtin_amdgcn_mfma_f32_16x16x32_bf16(af[mi], bf[ni], acc[mi][ni], 0, 0, 0);
    }
  }
#pragma unroll
  for (int mi = 0; mi < 4; mi++)
#pragma unroll
    for (int r = 0; r < 4; r++) {
      int row = m0 + wm * 64 + mi * 16 + fq * 4 + r;
      if (SCATTER) {
        int tok = pair_token[row];
        float w = pair_w[row];
#pragma unroll
        for (int ni = 0; ni < 4; ni++) {
          int col = n0 + wn * 64 + ni * 16 + fr;
          atomicAdd(&out[(long)tok * Dm + col], w * acc[mi][ni][r]);
        }
      } else {
#pragma unroll
        for (int ni = 0; ni < 4; ni++) {
          int col = n0 + wn * 64 + ni * 16 + fr;
          out[(long)row * Dm + col] = acc[mi][ni][r];
        }
      }
    }
}

// ---------------- launch ----------------

extern "C" void kernel_launch(void* const* d_in, const int* in_sizes, int n_in,
                              void* d_out, int out_size, void* d_ws, size_t ws_size,
                              hipStream_t stream) {
  const float* x    = (const float*)d_in[0];
  const float* gw   = (const float*)d_in[1];
  const float* bias = (const float*)d_in[2];
  const float* W1   = (const float*)d_in[3];
  const float* W3   = (const float*)d_in[4];
  const float* W2   = (const float*)d_in[5];
  const float* sw1  = (const float*)d_in[6];
  const float* sw3  = (const float*)d_in[7];
  const float* sw2  = (const float*)d_in[8];
  float* out = (float*)d_out;

  char* p = (char*)d_ws;
  auto alloc = [&](size_t bytes) {
    char* r = p; p += (bytes + 255) & ~(size_t)255; return r;
  };
  unsigned short* Xb   = (unsigned short*)alloc((size_t)Tn * Dm * 2);
  unsigned short* W1t  = (unsigned short*)alloc((size_t)En * In * Dm * 2);
  unsigned short* W3t  = (unsigned short*)alloc((size_t)En * In * Dm * 2);
  unsigned short* W2t  = (unsigned short*)alloc((size_t)En * Dm * In * 2);
  unsigned short* sw1b = (unsigned short*)alloc((size_t)SIn * Dm * 2);
  unsigned short* sw3b = (unsigned short*)alloc((size_t)SIn * Dm * 2);
  unsigned short* sw2b = (unsigned short*)alloc((size_t)Dm * SIn * 2);
  unsigned short* act  = (unsigned short*)alloc((size_t)CAP * In * 2);
  unsigned short* actS = (unsigned short*)alloc((size_t)Tn * SIn * 2);
  int*   route_e = (int*)alloc(Tn * 2 * 4);
  float* route_w = (float*)alloc(Tn * 2 * 4);
  int*   counts  = (int*)alloc(256);
  int*   offs    = (int*)alloc(256);
  int*   fill    = (int*)alloc(256);
  int*   ptok    = (int*)alloc(CAP * 4);
  float* pw      = (float*)alloc(CAP * 4);

  // conversions (inputs restored before every call -> must reconvert every call)
  convert_kernel<<<Tn * Dm / 4 / 256, 256, 0, stream>>>(x, Xb, Tn * Dm / 4);
  transpose_convert_kernel<<<dim3((Dm / 32) * (In / 32), En), 256, 0, stream>>>(W1, W1t, Dm, In);
  transpose_convert_kernel<<<dim3((Dm / 32) * (In / 32), En), 256, 0, stream>>>(W3, W3t, Dm, In);
  transpose_convert_kernel<<<dim3((In / 32) * (Dm / 32), En), 256, 0, stream>>>(W2, W2t, In, Dm);
  convert_kernel<<<SIn * Dm / 4 / 256, 256, 0, stream>>>(sw1, sw1b, SIn * Dm / 4);
  convert_kernel<<<SIn * Dm / 4 / 256, 256, 0, stream>>>(sw3, sw3b, SIn * Dm / 4);
  convert_kernel<<<Dm * SIn / 4 / 256, 256, 0, stream>>>(sw2, sw2b, Dm * SIn / 4);

  // routing
  init_counts_kernel<<<1, 64, 0, stream>>>(counts);
  router_kernel<<<Tn, 64, 0, stream>>>(x, gw, bias, route_e, route_w, counts);
  offsets_kernel<<<1, 1, 0, stream>>>(counts, offs, fill);
  init_pairs_kernel<<<CAP / 256, 256, 0, stream>>>(ptok, pw);
  scatter_kernel<<<Tn * 2 / 256, 256, 0, stream>>>(route_e, route_w, fill, ptok, pw);

  // expert + shared GEMMs
  h_gemm_kernel<true><<<dim3(CAP / 128, In / 128), 256, 0, stream>>>(
      Xb, W1t, W3t, act, ptok, offs, In, (long)In * Dm);
  h_gemm_kernel<false><<<dim3(Tn / 128, SIn / 128), 256, 0, stream>>>(
      Xb, sw1b, sw3b, actS, nullptr, nullptr, SIn, 0);
  o_gemm_kernel<false><<<dim3(Tn / 128, Dm / 128), 256, 0, stream>>>(
      actS, sw2b, out, nullptr, nullptr, nullptr, SIn, 0);   // plain store: fills all of out
  o_gemm_kernel<true><<<dim3(CAP / 128, Dm / 128), 256, 0, stream>>>(
      act, W2t, out, ptok, pw, offs, In, (long)Dm * In);     // atomic scatter on top
}

// Round 2
// 931.804 us; speedup vs baseline: 1.1519x; 1.1519x over previous
//
#include <hip/hip_runtime.h>

#define DEV __device__ __forceinline__

typedef __attribute__((ext_vector_type(8))) short short8;
typedef __attribute__((ext_vector_type(4))) float floatx4;

constexpr int Tn  = 4096;   // tokens (B*S)
constexpr int Dm  = 2048;   // model dim
constexpr int In  = 1408;   // expert inter dim
constexpr int En  = 8;      // experts
constexpr int SIn = 2816;   // shared inter dim (2*1408)
constexpr int CAP = 9216;   // 8192 pairs + 8*128 padding

DEV unsigned short f2bf(float f) {          // fp32 -> bf16 RNE
  unsigned int u = __float_as_uint(f);
  u += 0x7FFF + ((u >> 16) & 1);
  return (unsigned short)(u >> 16);
}

DEV float bf2f(unsigned short u) {
  return __uint_as_float(((unsigned int)u) << 16);
}

DEV void gl2lds16(const unsigned short* g, unsigned short* l) {
  // async global->LDS, 16B/lane; LDS dst = uniform base + lane*16
  __builtin_amdgcn_global_load_lds(
      (const __attribute__((address_space(1))) unsigned int*)g,
      (__attribute__((address_space(3))) unsigned int*)l, 16, 0, 0);
}

// fragment address with XOR bank swizzle (matches swizzled staging below):
// global chunk c of row r lives at LDS chunk position c ^ (r&7)
DEV int fragaddr(int row, int chunk) {
  return row * 64 + ((chunk ^ (row & 7)) * 8);
}

// ---------------- conversion kernels ----------------

__global__ void convert_kernel(const float* __restrict__ src,
                               unsigned short* __restrict__ dst, int n4) {
  int i = blockIdx.x * 256 + threadIdx.x;
  if (i >= n4) return;
  float4 v = ((const float4*)src)[i];
  union { unsigned short u[4]; unsigned long long ll; } p;
  p.u[0] = f2bf(v.x); p.u[1] = f2bf(v.y); p.u[2] = f2bf(v.z); p.u[3] = f2bf(v.w);
  *(unsigned long long*)(dst + (long)i * 4) = p.ll;
}

// src [E][R][C] fp32 -> dst [E][C][R] bf16 (transpose per expert)
__global__ void transpose_convert_kernel(const float* __restrict__ src,
                                         unsigned short* __restrict__ dst,
                                         int R, int C) {
  __shared__ float tile[32][33];
  int tilesC = C >> 5;
  int tr = (blockIdx.x / tilesC) << 5;
  int tc = (blockIdx.x % tilesC) << 5;
  const float* s = src + (long)blockIdx.y * R * C;
  unsigned short* d = dst + (long)blockIdx.y * R * C;
  int tx = threadIdx.x & 31, ty = threadIdx.x >> 5;   // 32 x 8
#pragma unroll
  for (int i = 0; i < 4; i++)
    tile[ty + 8 * i][tx] = s[(long)(tr + ty + 8 * i) * C + tc + tx];
  __syncthreads();
#pragma unroll
  for (int i = 0; i < 4; i++)
    d[(long)(tc + ty + 8 * i) * R + tr + tx] = f2bf(tile[tx][ty + 8 * i]);
}

// ---------------- routing ----------------

__global__ void init_counts_kernel(int* counts) {
  if (threadIdx.x < En) counts[threadIdx.x] = 0;
}

// one wave per token; fp64 scores so top-k matches the numpy reference
__global__ void router_kernel(const float* __restrict__ X, const float* __restrict__ GW,
                              const float* __restrict__ bias,
                              int* __restrict__ route_e, float* __restrict__ route_w,
                              int* __restrict__ counts) {
  int t = blockIdx.x, lane = threadIdx.x;
  const float* xr = X + (long)t * Dm;
  double acc[En];
#pragma unroll
  for (int e = 0; e < En; e++) acc[e] = 0.0;
  for (int d = lane; d < Dm; d += 64) {
    double xv = (double)xr[d];
#pragma unroll
    for (int e = 0; e < En; e++) acc[e] += xv * (double)GW[e * Dm + d];
  }
#pragma unroll
  for (int off = 32; off > 0; off >>= 1) {
#pragma unroll
    for (int e = 0; e < En; e++) acc[e] += __shfl_down(acc[e], off);
  }
  if (lane == 0) {
    double sc[En], sel[En];
#pragma unroll
    for (int e = 0; e < En; e++) {
      sc[e] = 1.0 / (1.0 + exp(-acc[e]));
      sel[e] = sc[e] + (double)bias[e];
    }
    int i0 = 0;
#pragma unroll
    for (int e = 1; e < En; e++) if (sel[e] > sel[i0]) i0 = e;
    int i1 = (i0 == 0) ? 1 : 0;
#pragma unroll
    for (int e = 0; e < En; e++) if (e != i0 && sel[e] > sel[i1]) i1 = e;
    double s = sc[i0] + sc[i1];
    if (s < 1e-12) s = 1e-12;
    route_e[t * 2] = i0;  route_e[t * 2 + 1] = i1;
    route_w[t * 2] = (float)(sc[i0] / s);  route_w[t * 2 + 1] = (float)(sc[i1] / s);
    atomicAdd(&counts[i0], 1);  atomicAdd(&counts[i1], 1);
  }
}

__global__ void offsets_kernel(const int* __restrict__ counts,
                               int* __restrict__ offs, int* __restrict__ fill) {
  if (threadIdx.x == 0) {
    int off = 0;
    for (int e = 0; e < En; e++) {
      offs[e] = off; fill[e] = off;
      off += (counts[e] + 127) & ~127;      // pad each expert segment to 128
    }
    offs[En] = off;
  }
}

__global__ void init_pairs_kernel(int* pt) {
  int i = blockIdx.x * 256 + threadIdx.x;
  if (i < CAP) pt[i] = 0;                   // pads gather token 0 (harmless)
}

__global__ void scatter_kernel(const int* __restrict__ re, int* __restrict__ fill,
                               int* __restrict__ pt, int* __restrict__ pslot) {
  int i = blockIdx.x * 256 + threadIdx.x;
  if (i < Tn * 2) {
    int e = re[i];
    int slot = atomicAdd(&fill[e], 1);
    pt[slot] = i >> 1;
    pslot[i] = slot;                        // inverse map pair -> slot
  }
}

// ---------------- GEMM stage 1: h = silu(A@W1) * (A@W3) ----------------
// A rows gathered via pair_token (routed) or identity (shared).
// B1/B3 are B^T layout [N][K] bf16. Output act [rows][N] bf16.

template<bool GATHER>
__global__ __launch_bounds__(256, 2)
void h_gemm_kernel(const unsigned short* __restrict__ A,
                   const unsigned short* __restrict__ B1b,
                   const unsigned short* __restrict__ B3b,
                   unsigned short* __restrict__ act,
                   const int* __restrict__ pair_token,
                   const int* __restrict__ offs,
                   int N, long estride) {
  __shared__ unsigned short sA[128 * 64];
  __shared__ unsigned short sB1[128 * 64];
  __shared__ unsigned short sB3[128 * 64];
  const int Kd = Dm;
  int m0 = blockIdx.x * 128, n0 = blockIdx.y * 128;
  const unsigned short* B1p = B1b;
  const unsigned short* B3p = B3b;
  if (GATHER) {
    if (m0 >= offs[En]) return;                    // beyond padded total
    int e = 0;
    while (!(m0 >= offs[e] && m0 < offs[e + 1])) e++;
    B1p += (long)e * estride;
    B3p += (long)e * estride;
  }
  int tid = threadIdx.x, wave = tid >> 6, lane = tid & 63;
  int lr = lane >> 3, lc = lane & 7;
  int lcs = lc ^ lr;                               // XOR bank swizzle on fetch
  const unsigned short *gA[4], *gB1[4], *gB3[4];
#pragma unroll
  for (int j = 0; j < 4; j++) {
    int r = wave * 32 + j * 8 + lr;
    long arow = GATHER ? (long)pair_token[m0 + r] : (long)(m0 + r);
    gA[j]  = A   + arow * Kd + lcs * 8;
    gB1[j] = B1p + (long)(n0 + r) * Kd + lcs * 8;
    gB3[j] = B3p + (long)(n0 + r) * Kd + lcs * 8;
  }
  int wm = wave >> 1, wn = wave & 1;
  int fr = lane & 15, fq = lane >> 4;
  floatx4 acc1[4][4], acc3[4][4];
#pragma unroll
  for (int mi = 0; mi < 4; mi++)
#pragma unroll
    for (int ni = 0; ni < 4; ni++) { acc1[mi][ni] = (floatx4)0.0f; acc3[mi][ni] = (floatx4)0.0f; }

  for (int k0 = 0; k0 < Kd; k0 += 64) {
    __syncthreads();
#pragma unroll
    for (int j = 0; j < 4; j++) {
      int rb = (wave * 32 + j * 8) * 64;
      gl2lds16(gA[j]  + k0, &sA[rb]);
      gl2lds16(gB1[j] + k0, &sB1[rb]);
      gl2lds16(gB3[j] + k0, &sB3[rb]);
    }
    __syncthreads();
#pragma unroll
    for (int kk = 0; kk < 2; kk++) {
      short8 af[4], b1f[4], b3f[4];
#pragma unroll
      for (int i = 0; i < 4; i++) {
        af[i]  = *(const short8*)&sA [fragaddr(wm * 64 + i * 16 + fr, kk * 4 + fq)];
        b1f[i] = *(const short8*)&sB1[fragaddr(wn * 64 + i * 16 + fr, kk * 4 + fq)];
        b3f[i] = *(const short8*)&sB3[fragaddr(wn * 64 + i * 16 + fr, kk * 4 + fq)];
      }
#pragma unroll
      for (int mi = 0; mi < 4; mi++)
#pragma unroll
        for (int ni = 0; ni < 4; ni++) {
          acc1[mi][ni] = __builtin_amdgcn_mfma_f32_16x16x32_bf16(af[mi], b1f[ni], acc1[mi][ni], 0, 0, 0);
          acc3[mi][ni] = __builtin_amdgcn_mfma_f32_16x16x32_bf16(af[mi], b3f[ni], acc3[mi][ni], 0, 0, 0);
        }
    }
  }
  // epilogue: act = bf16( silu(h1) * h3 );  C/D layout: col=lane&15, row=(lane>>4)*4+reg
#pragma unroll
  for (int mi = 0; mi < 4; mi++)
#pragma unroll
    for (int ni = 0; ni < 4; ni++)
#pragma unroll
      for (int r = 0; r < 4; r++) {
        int row = m0 + wm * 64 + mi * 16 + fq * 4 + r;
        int col = n0 + wn * 64 + ni * 16 + fr;
        float h1 = acc1[mi][ni][r], h3 = acc3[mi][ni][r];
        float v = h1 / (1.0f + __expf(-h1)) * h3;
        act[(long)row * N + col] = f2bf(v);
      }
}

// ---------------- GEMM stage 2: out = act @ W2 ----------------
// ROUTED: per-expert B, plain bf16 stores to yR (combined later).
// else:   shared expert, fp32 stores straight into d_out.

template<bool ROUTED>
__global__ __launch_bounds__(256, 2)
void o_gemm_kernel(const unsigned short* __restrict__ A,
                   const unsigned short* __restrict__ Bb,
                   float* __restrict__ outF,
                   unsigned short* __restrict__ outB,
                   const int* __restrict__ offs,
                   int Kd, long estride) {
  __shared__ unsigned short sA[128 * 64];
  __shared__ unsigned short sB[128 * 64];
  int m0 = blockIdx.x * 128, n0 = blockIdx.y * 128;
  const unsigned short* Bp = Bb;
  if (ROUTED) {
    if (m0 >= offs[En]) return;
    int e = 0;
    while (!(m0 >= offs[e] && m0 < offs[e + 1])) e++;
    Bp += (long)e * estride;
  }
  int tid = threadIdx.x, wave = tid >> 6, lane = tid & 63;
  int lr = lane >> 3, lc = lane & 7;
  int lcs = lc ^ lr;
  const unsigned short *gA[4], *gB[4];
#pragma unroll
  for (int j = 0; j < 4; j++) {
    int r = wave * 32 + j * 8 + lr;
    gA[j] = A  + (long)(m0 + r) * Kd + lcs * 8;
    gB[j] = Bp + (long)(n0 + r) * Kd + lcs * 8;
  }
  int wm = wave >> 1, wn = wave & 1;
  int fr = lane & 15, fq = lane >> 4;
  floatx4 acc[4][4];
#pragma unroll
  for (int mi = 0; mi < 4; mi++)
#pragma unroll
    for (int ni = 0; ni < 4; ni++) acc[mi][ni] = (floatx4)0.0f;

  for (int k0 = 0; k0 < Kd; k0 += 64) {
    __syncthreads();
#pragma unroll
    for (int j = 0; j < 4; j++) {
      int rb = (wave * 32 + j * 8) * 64;
      gl2lds16(gA[j] + k0, &sA[rb]);
      gl2lds16(gB[j] + k0, &sB[rb]);
    }
    __syncthreads();
#pragma unroll
    for (int kk = 0; kk < 2; kk++) {
      short8 af[4], bf[4];
#pragma unroll
      for (int i = 0; i < 4; i++) {
        af[i] = *(const short8*)&sA[fragaddr(wm * 64 + i * 16 + fr, kk * 4 + fq)];
        bf[i] = *(const short8*)&sB[fragaddr(wn * 64 + i * 16 + fr, kk * 4 + fq)];
      }
#pragma unroll
      for (int mi = 0; mi < 4; mi++)
#pragma unroll
        for (int ni = 0; ni < 4; ni++)
          acc[mi][ni] = __builtin_amdgcn_mfma_f32_16x16x32_bf16(af[mi], bf[ni], acc[mi][ni], 0, 0, 0);
    }
  }
#pragma unroll
  for (int mi = 0; mi < 4; mi++)
#pragma unroll
    for (int r = 0; r < 4; r++) {
      int row = m0 + wm * 64 + mi * 16 + fq * 4 + r;
#pragma unroll
      for (int ni = 0; ni < 4; ni++) {
        int col = n0 + wn * 64 + ni * 16 + fr;
        if (ROUTED) outB[(long)row * Dm + col] = f2bf(acc[mi][ni][r]);
        else        outF[(long)row * Dm + col] = acc[mi][ni][r];
      }
    }
}

// ---------------- combine: out[t] += w0*yR[s0] + w1*yR[s1] ----------------

__global__ void combine_kernel(const unsigned short* __restrict__ yR,
                               const int* __restrict__ pslot,
                               const float* __restrict__ rw,
                               float* __restrict__ out) {
  int idx = blockIdx.x * 256 + threadIdx.x;   // Tn * (Dm/4) threads
  int t = idx >> 9, c4 = idx & 511;           // Dm/4 = 512
  int s0 = pslot[t * 2], s1 = pslot[t * 2 + 1];
  float w0 = rw[t * 2], w1 = rw[t * 2 + 1];
  ushort4 a = ((const ushort4*)(yR + (long)s0 * Dm))[c4];
  ushort4 b = ((const ushort4*)(yR + (long)s1 * Dm))[c4];
  float4* op = (float4*)(out + (long)t * Dm) + c4;
  float4 o = *op;
  o.x += w0 * bf2f(a.x) + w1 * bf2f(b.x);
  o.y += w0 * bf2f(a.y) + w1 * bf2f(b.y);
  o.z += w0 * bf2f(a.z) + w1 * bf2f(b.z);
  o.w += w0 * bf2f(a.w) + w1 * bf2f(b.w);
  *op = o;
}

// ---------------- launch ----------------

extern "C" void kernel_launch(void* const* d_in, const int* in_sizes, int n_in,
                              void* d_out, int out_size, void* d_ws, size_t ws_size,
                              hipStream_t stream) {
  const float* x    = (const float*)d_in[0];
  const float* gw   = (const float*)d_in[1];
  const float* bias = (const float*)d_in[2];
  const float* W1   = (const float*)d_in[3];
  const float* W3   = (const float*)d_in[4];
  const float* W2   = (const float*)d_in[5];
  const float* sw1  = (const float*)d_in[6];
  const float* sw3  = (const float*)d_in[7];
  const float* sw2  = (const float*)d_in[8];
  float* out = (float*)d_out;

  char* p = (char*)d_ws;
  auto alloc = [&](size_t bytes) {
    char* r = p; p += (bytes + 255) & ~(size_t)255; return r;
  };
  unsigned short* Xb   = (unsigned short*)alloc((size_t)Tn * Dm * 2);
  unsigned short* W1t  = (unsigned short*)alloc((size_t)En * In * Dm * 2);
  unsigned short* W3t  = (unsigned short*)alloc((size_t)En * In * Dm * 2);
  unsigned short* W2t  = (unsigned short*)alloc((size_t)En * Dm * In * 2);
  unsigned short* sw1b = (unsigned short*)alloc((size_t)SIn * Dm * 2);
  unsigned short* sw3b = (unsigned short*)alloc((size_t)SIn * Dm * 2);
  unsigned short* sw2b = (unsigned short*)alloc((size_t)Dm * SIn * 2);
  unsigned short* act  = (unsigned short*)alloc((size_t)CAP * In * 2);
  unsigned short* actS = (unsigned short*)alloc((size_t)Tn * SIn * 2);
  unsigned short* yR   = (unsigned short*)alloc((size_t)CAP * Dm * 2);
  int*   route_e = (int*)alloc(Tn * 2 * 4);
  float* route_w = (float*)alloc(Tn * 2 * 4);
  int*   counts  = (int*)alloc(256);
  int*   offs    = (int*)alloc(256);
  int*   fill    = (int*)alloc(256);
  int*   ptok    = (int*)alloc(CAP * 4);
  int*   pslot   = (int*)alloc(Tn * 2 * 4);

  // conversions (inputs restored before every call -> must reconvert every call)
  convert_kernel<<<Tn * Dm / 4 / 256, 256, 0, stream>>>(x, Xb, Tn * Dm / 4);
  transpose_convert_kernel<<<dim3((Dm / 32) * (In / 32), En), 256, 0, stream>>>(W1, W1t, Dm, In);
  transpose_convert_kernel<<<dim3((Dm / 32) * (In / 32), En), 256, 0, stream>>>(W3, W3t, Dm, In);
  transpose_convert_kernel<<<dim3((In / 32) * (Dm / 32), En), 256, 0, stream>>>(W2, W2t, In, Dm);
  convert_kernel<<<SIn * Dm / 4 / 256, 256, 0, stream>>>(sw1, sw1b, SIn * Dm / 4);
  convert_kernel<<<SIn * Dm / 4 / 256, 256, 0, stream>>>(sw3, sw3b, SIn * Dm / 4);
  convert_kernel<<<Dm * SIn / 4 / 256, 256, 0, stream>>>(sw2, sw2b, Dm * SIn / 4);

  // routing
  init_counts_kernel<<<1, 64, 0, stream>>>(counts);
  router_kernel<<<Tn, 64, 0, stream>>>(x, gw, bias, route_e, route_w, counts);
  offsets_kernel<<<1, 1, 0, stream>>>(counts, offs, fill);
  init_pairs_kernel<<<CAP / 256, 256, 0, stream>>>(ptok);
  scatter_kernel<<<Tn * 2 / 256, 256, 0, stream>>>(route_e, fill, ptok, pslot);

  // expert + shared GEMMs
  h_gemm_kernel<true><<<dim3(CAP / 128, In / 128), 256, 0, stream>>>(
      Xb, W1t, W3t, act, ptok, offs, In, (long)In * Dm);
  h_gemm_kernel<false><<<dim3(Tn / 128, SIn / 128), 256, 0, stream>>>(
      Xb, sw1b, sw3b, actS, nullptr, nullptr, SIn, 0);
  o_gemm_kernel<false><<<dim3(Tn / 128, Dm / 128), 256, 0, stream>>>(
      actS, sw2b, out, nullptr, nullptr, SIn, 0);            // fills all of out (fp32)
  o_gemm_kernel<true><<<dim3(CAP / 128, Dm / 128), 256, 0, stream>>>(
      act, W2t, nullptr, yR, offs, In, (long)Dm * In);       // bf16 rows, no atomics
  combine_kernel<<<Tn * (Dm / 4) / 256, 256, 0, stream>>>(yR, pslot, route_w, out);
}

// Round 3
// 862.534 us; speedup vs baseline: 1.2444x; 1.0803x over previous
//
#include <hip/hip_runtime.h>

#define DEV __device__ __forceinline__

typedef __attribute__((ext_vector_type(8))) short short8;
typedef __attribute__((ext_vector_type(4))) float floatx4;

constexpr int Tn  = 4096;   // tokens (B*S)
constexpr int Dm  = 2048;   // model dim
constexpr int In  = 1408;   // expert inter dim
constexpr int En  = 8;      // experts
constexpr int SIn = 2816;   // shared inter dim (2*1408)
constexpr int CAP = 9216;   // 8192 pairs + 8*128 padding

// merged-grid split points
constexpr int RT_H = (CAP / 128) * (In / 128);    // 72*11 = 792 routed h blocks
constexpr int SH_H = (Tn / 128) * (SIn / 128);    // 32*22 = 704 shared h blocks
constexpr int RT_O = (CAP / 128) * (Dm / 128);    // 72*16 = 1152 routed o blocks
constexpr int SH_O = (Tn / 128) * (Dm / 128);     // 32*16 = 512 shared o blocks

DEV unsigned short f2bf(float f) {          // fp32 -> bf16 RNE
  unsigned int u = __float_as_uint(f);
  u += 0x7FFF + ((u >> 16) & 1);
  return (unsigned short)(u >> 16);
}

DEV float bf2f(unsigned short u) {
  return __uint_as_float(((unsigned int)u) << 16);
}

DEV void gl2lds16(const unsigned short* g, unsigned short* l) {
  // async global->LDS, 16B/lane; LDS dst = uniform base + lane*16
  __builtin_amdgcn_global_load_lds(
      (const __attribute__((address_space(1))) unsigned int*)g,
      (__attribute__((address_space(3))) unsigned int*)l, 16, 0, 0);
}

// fragment address with XOR bank swizzle (matches swizzled staging):
// global chunk c of row r lives at LDS chunk position c ^ (r&7)
DEV int fragaddr(int row, int chunk) {
  return row * 64 + ((chunk ^ (row & 7)) * 8);
}

// ---------------- merged conversion kernels ----------------

// y=0: x, y=1: sw1, y=2: sw3, y=3: sw2  (flat fp32 -> bf16)
__global__ void convert_all_kernel(const float* __restrict__ x,
                                   const float* __restrict__ sw1,
                                   const float* __restrict__ sw3,
                                   const float* __restrict__ sw2,
                                   unsigned short* __restrict__ Xb,
                                   unsigned short* __restrict__ sw1b,
                                   unsigned short* __restrict__ sw3b,
                                   unsigned short* __restrict__ sw2b) {
  int y = blockIdx.y;
  const float* src; unsigned short* dst; int n4;
  if (y == 0)      { src = x;   dst = Xb;   n4 = Tn * Dm / 4; }
  else if (y == 1) { src = sw1; dst = sw1b; n4 = SIn * Dm / 4; }
  else if (y == 2) { src = sw3; dst = sw3b; n4 = SIn * Dm / 4; }
  else             { src = sw2; dst = sw2b; n4 = Dm * SIn / 4; }
  int i = blockIdx.x * 256 + threadIdx.x;
  if (i >= n4) return;
  float4 v = ((const float4*)src)[i];
  union { unsigned short u[4]; unsigned long long ll; } p;
  p.u[0] = f2bf(v.x); p.u[1] = f2bf(v.y); p.u[2] = f2bf(v.z); p.u[3] = f2bf(v.w);
  *(unsigned long long*)(dst + (long)i * 4) = p.ll;
}

// z=0: W1 [E][Dm][In], z=1: W3 same, z=2: W2 [E][In][Dm]  ->  [E][C][R] bf16
// tile count (R/32)*(C/32) = 64*44 = 44*64 = 2816 for all three.
__global__ void transpose_all_kernel(const float* __restrict__ W1,
                                     const float* __restrict__ W3,
                                     const float* __restrict__ W2,
                                     unsigned short* __restrict__ W1t,
                                     unsigned short* __restrict__ W3t,
                                     unsigned short* __restrict__ W2t) {
  __shared__ float tile[32][33];
  int z = blockIdx.z;
  const float* s0; unsigned short* d0; int R, C;
  if (z == 0)      { s0 = W1; d0 = W1t; R = Dm; C = In; }
  else if (z == 1) { s0 = W3; d0 = W3t; R = Dm; C = In; }
  else             { s0 = W2; d0 = W2t; R = In; C = Dm; }
  int tilesC = C >> 5;
  int tr = (blockIdx.x / tilesC) << 5;
  int tc = (blockIdx.x % tilesC) << 5;
  const float* s = s0 + (long)blockIdx.y * R * C;
  unsigned short* d = d0 + (long)blockIdx.y * R * C;
  int tx = threadIdx.x & 31, ty = threadIdx.x >> 5;   // 32 x 8
#pragma unroll
  for (int i = 0; i < 4; i++)
    tile[ty + 8 * i][tx] = s[(long)(tr + ty + 8 * i) * C + tc + tx];
  __syncthreads();
#pragma unroll
  for (int i = 0; i < 4; i++)
    d[(long)(tc + ty + 8 * i) * R + tr + tx] = f2bf(tile[tx][ty + 8 * i]);
}

// ---------------- routing ----------------

__global__ void init_kernel(int* counts, int* ptok) {
  int i = blockIdx.x * 256 + threadIdx.x;
  if (i < En) counts[i] = 0;
  if (i < CAP) ptok[i] = 0;                 // pads gather token 0 (harmless)
}

// one wave per token; fp64 scores so top-k matches the numpy reference
__global__ void router_kernel(const float* __restrict__ X, const float* __restrict__ GW,
                              const float* __restrict__ bias,
                              int* __restrict__ route_e, float* __restrict__ route_w,
                              int* __restrict__ counts) {
  int t = blockIdx.x, lane = threadIdx.x;
  const float* xr = X + (long)t * Dm;
  double acc[En];
#pragma unroll
  for (int e = 0; e < En; e++) acc[e] = 0.0;
  for (int d = lane; d < Dm; d += 64) {
    double xv = (double)xr[d];
#pragma unroll
    for (int e = 0; e < En; e++) acc[e] += xv * (double)GW[e * Dm + d];
  }
#pragma unroll
  for (int off = 32; off > 0; off >>= 1) {
#pragma unroll
    for (int e = 0; e < En; e++) acc[e] += __shfl_down(acc[e], off);
  }
  if (lane == 0) {
    double sc[En], sel[En];
#pragma unroll
    for (int e = 0; e < En; e++) {
      sc[e] = 1.0 / (1.0 + exp(-acc[e]));
      sel[e] = sc[e] + (double)bias[e];
    }
    int i0 = 0;
#pragma unroll
    for (int e = 1; e < En; e++) if (sel[e] > sel[i0]) i0 = e;
    int i1 = (i0 == 0) ? 1 : 0;
#pragma unroll
    for (int e = 0; e < En; e++) if (e != i0 && sel[e] > sel[i1]) i1 = e;
    double s = sc[i0] + sc[i1];
    if (s < 1e-12) s = 1e-12;
    route_e[t * 2] = i0;  route_e[t * 2 + 1] = i1;
    route_w[t * 2] = (float)(sc[i0] / s);  route_w[t * 2 + 1] = (float)(sc[i1] / s);
    atomicAdd(&counts[i0], 1);  atomicAdd(&counts[i1], 1);
  }
}

__global__ void offsets_kernel(const int* __restrict__ counts,
                               int* __restrict__ offs, int* __restrict__ fill) {
  if (threadIdx.x == 0) {
    int off = 0;
    for (int e = 0; e < En; e++) {
      offs[e] = off; fill[e] = off;
      off += (counts[e] + 127) & ~127;      // pad each expert segment to 128
    }
    offs[En] = off;
  }
}

__global__ void scatter_kernel(const int* __restrict__ re, int* __restrict__ fill,
                               int* __restrict__ pt, int* __restrict__ pslot) {
  int i = blockIdx.x * 256 + threadIdx.x;
  if (i < Tn * 2) {
    int e = re[i];
    int slot = atomicAdd(&fill[e], 1);
    pt[slot] = i >> 1;
    pslot[i] = slot;                        // inverse map pair -> slot
  }
}

// ---------------- merged GEMM stage 1: h = silu(A@W1) * (A@W3) ----------------
// blocks [0, RT_H): routed (gathered A rows, per-expert W1/W3, out act[.][In])
// blocks [RT_H, RT_H+SH_H): shared (identity rows, sw1/sw3, out actS[.][SIn])

__global__ __launch_bounds__(256, 2)
void h_gemm_all(const unsigned short* __restrict__ Xb,
                const unsigned short* __restrict__ W1t,
                const unsigned short* __restrict__ W3t,
                const unsigned short* __restrict__ sw1b,
                const unsigned short* __restrict__ sw3b,
                unsigned short* __restrict__ act,
                unsigned short* __restrict__ actS,
                const int* __restrict__ ptok,
                const int* __restrict__ offs) {
  __shared__ unsigned short sA[128 * 64];
  __shared__ unsigned short sB1[128 * 64];
  __shared__ unsigned short sB3[128 * 64];
  const int Kd = Dm;
  int bid = blockIdx.x;
  bool routed = bid < RT_H;
  int m0, n0, N;
  const unsigned short *B1p, *B3p;
  unsigned short* ap;
  if (routed) {
    m0 = (bid % 72) * 128; n0 = (bid / 72) * 128;
    if (m0 >= offs[En]) return;                    // beyond padded total
    int e = 0;
    while (!(m0 >= offs[e] && m0 < offs[e + 1])) e++;
    B1p = W1t + (long)e * In * Dm;
    B3p = W3t + (long)e * In * Dm;
    ap = act; N = In;
  } else {
    int b2 = bid - RT_H;
    m0 = (b2 % 32) * 128; n0 = (b2 / 32) * 128;
    B1p = sw1b; B3p = sw3b;
    ap = actS; N = SIn;
  }
  int tid = threadIdx.x, wave = tid >> 6, lane = tid & 63;
  int lr = lane >> 3, lc = lane & 7;
  int lcs = lc ^ lr;                               // XOR bank swizzle on fetch
  const unsigned short *gA[4], *gB1[4], *gB3[4];
#pragma unroll
  for (int j = 0; j < 4; j++) {
    int r = wave * 32 + j * 8 + lr;
    long arow = routed ? (long)ptok[m0 + r] : (long)(m0 + r);
    gA[j]  = Xb  + arow * Kd + lcs * 8;
    gB1[j] = B1p + (long)(n0 + r) * Kd + lcs * 8;
    gB3[j] = B3p + (long)(n0 + r) * Kd + lcs * 8;
  }
  int wm = wave >> 1, wn = wave & 1;
  int fr = lane & 15, fq = lane >> 4;
  floatx4 acc1[4][4], acc3[4][4];
#pragma unroll
  for (int mi = 0; mi < 4; mi++)
#pragma unroll
    for (int ni = 0; ni < 4; ni++) { acc1[mi][ni] = (floatx4)0.0f; acc3[mi][ni] = (floatx4)0.0f; }

  for (int k0 = 0; k0 < Kd; k0 += 64) {
    __syncthreads();
#pragma unroll
    for (int j = 0; j < 4; j++) {
      int rb = (wave * 32 + j * 8) * 64;
      gl2lds16(gA[j]  + k0, &sA[rb]);
      gl2lds16(gB1[j] + k0, &sB1[rb]);
      gl2lds16(gB3[j] + k0, &sB3[rb]);
    }
    __syncthreads();
#pragma unroll
    for (int kk = 0; kk < 2; kk++) {
      short8 af[4], b1f[4], b3f[4];
#pragma unroll
      for (int i = 0; i < 4; i++) {
        af[i]  = *(const short8*)&sA [fragaddr(wm * 64 + i * 16 + fr, kk * 4 + fq)];
        b1f[i] = *(const short8*)&sB1[fragaddr(wn * 64 + i * 16 + fr, kk * 4 + fq)];
        b3f[i] = *(const short8*)&sB3[fragaddr(wn * 64 + i * 16 + fr, kk * 4 + fq)];
      }
#pragma unroll
      for (int mi = 0; mi < 4; mi++)
#pragma unroll
        for (int ni = 0; ni < 4; ni++) {
          acc1[mi][ni] = __builtin_amdgcn_mfma_f32_16x16x32_bf16(af[mi], b1f[ni], acc1[mi][ni], 0, 0, 0);
          acc3[mi][ni] = __builtin_amdgcn_mfma_f32_16x16x32_bf16(af[mi], b3f[ni], acc3[mi][ni], 0, 0, 0);
        }
    }
  }
  // epilogue: act = bf16( silu(h1) * h3 );  C/D layout: col=lane&15, row=(lane>>4)*4+reg
#pragma unroll
  for (int mi = 0; mi < 4; mi++)
#pragma unroll
    for (int ni = 0; ni < 4; ni++)
#pragma unroll
      for (int r = 0; r < 4; r++) {
        int row = m0 + wm * 64 + mi * 16 + fq * 4 + r;
        int col = n0 + wn * 64 + ni * 16 + fr;
        float h1 = acc1[mi][ni][r], h3 = acc3[mi][ni][r];
        float v = h1 / (1.0f + __expf(-h1)) * h3;
        ap[(long)row * N + col] = f2bf(v);
      }
}

// ---------------- merged GEMM stage 2: out = act @ W2 ----------------
// blocks [0, RT_O): routed (A=act lda=In, B=W2t per expert, bf16 -> yR)
// blocks [RT_O, RT_O+SH_O): shared (A=actS lda=SIn, B=sw2b, fp32 -> out, fills d_out)

__global__ __launch_bounds__(256, 2)
void o_gemm_all(const unsigned short* __restrict__ act,
                const unsigned short* __restrict__ actS,
                const unsigned short* __restrict__ W2t,
                const unsigned short* __restrict__ sw2b,
                unsigned short* __restrict__ yR,
                float* __restrict__ out,
                const int* __restrict__ offs) {
  __shared__ unsigned short sA[128 * 64];
  __shared__ unsigned short sB[128 * 64];
  int bid = blockIdx.x;
  bool routed = bid < RT_O;
  int m0, n0, Kd;
  const unsigned short *Ap, *Bp;
  if (routed) {
    m0 = (bid % 72) * 128; n0 = (bid / 72) * 128;
    if (m0 >= offs[En]) return;
    int e = 0;
    while (!(m0 >= offs[e] && m0 < offs[e + 1])) e++;
    Ap = act; Bp = W2t + (long)e * Dm * In; Kd = In;
  } else {
    int b2 = bid - RT_O;
    m0 = (b2 % 32) * 128; n0 = (b2 / 32) * 128;
    Ap = actS; Bp = sw2b; Kd = SIn;
  }
  int tid = threadIdx.x, wave = tid >> 6, lane = tid & 63;
  int lr = lane >> 3, lc = lane & 7;
  int lcs = lc ^ lr;
  const unsigned short *gA[4], *gB[4];
#pragma unroll
  for (int j = 0; j < 4; j++) {
    int r = wave * 32 + j * 8 + lr;
    gA[j] = Ap + (long)(m0 + r) * Kd + lcs * 8;
    gB[j] = Bp + (long)(n0 + r) * Kd + lcs * 8;
  }
  int wm = wave >> 1, wn = wave & 1;
  int fr = lane & 15, fq = lane >> 4;
  floatx4 acc[4][4];
#pragma unroll
  for (int mi = 0; mi < 4; mi++)
#pragma unroll
    for (int ni = 0; ni < 4; ni++) acc[mi][ni] = (floatx4)0.0f;

  for (int k0 = 0; k0 < Kd; k0 += 64) {
    __syncthreads();
#pragma unroll
    for (int j = 0; j < 4; j++) {
      int rb = (wave * 32 + j * 8) * 64;
      gl2lds16(gA[j] + k0, &sA[rb]);
      gl2lds16(gB[j] + k0, &sB[rb]);
    }
    __syncthreads();
#pragma unroll
    for (int kk = 0; kk < 2; kk++) {
      short8 af[4], bf[4];
#pragma unroll
      for (int i = 0; i < 4; i++) {
        af[i] = *(const short8*)&sA[fragaddr(wm * 64 + i * 16 + fr, kk * 4 + fq)];
        bf[i] = *(const short8*)&sB[fragaddr(wn * 64 + i * 16 + fr, kk * 4 + fq)];
      }
#pragma unroll
      for (int mi = 0; mi < 4; mi++)
#pragma unroll
        for (int ni = 0; ni < 4; ni++)
          acc[mi][ni] = __builtin_amdgcn_mfma_f32_16x16x32_bf16(af[mi], bf[ni], acc[mi][ni], 0, 0, 0);
    }
  }
#pragma unroll
  for (int mi = 0; mi < 4; mi++)
#pragma unroll
    for (int r = 0; r < 4; r++) {
      int row = m0 + wm * 64 + mi * 16 + fq * 4 + r;
#pragma unroll
      for (int ni = 0; ni < 4; ni++) {
        int col = n0 + wn * 64 + ni * 16 + fr;
        if (routed) yR[(long)row * Dm + col] = f2bf(acc[mi][ni][r]);
        else        out[(long)row * Dm + col] = acc[mi][ni][r];
      }
    }
}

// ---------------- combine: out[t] += w0*yR[s0] + w1*yR[s1] ----------------

__global__ void combine_kernel(const unsigned short* __restrict__ yR,
                               const int* __restrict__ pslot,
                               const float* __restrict__ rw,
                               float* __restrict__ out) {
  int idx = blockIdx.x * 256 + threadIdx.x;   // Tn * (Dm/4) threads
  int t = idx >> 9, c4 = idx & 511;           // Dm/4 = 512
  int s0 = pslot[t * 2], s1 = pslot[t * 2 + 1];
  float w0 = rw[t * 2], w1 = rw[t * 2 + 1];
  ushort4 a = ((const ushort4*)(yR + (long)s0 * Dm))[c4];
  ushort4 b = ((const ushort4*)(yR + (long)s1 * Dm))[c4];
  float4* op = (float4*)(out + (long)t * Dm) + c4;
  float4 o = *op;
  o.x += w0 * bf2f(a.x) + w1 * bf2f(b.x);
  o.y += w0 * bf2f(a.y) + w1 * bf2f(b.y);
  o.z += w0 * bf2f(a.z) + w1 * bf2f(b.z);
  o.w += w0 * bf2f(a.w) + w1 * bf2f(b.w);
  *op = o;
}

// ---------------- launch ----------------

extern "C" void kernel_launch(void* const* d_in, const int* in_sizes, int n_in,
                              void* d_out, int out_size, void* d_ws, size_t ws_size,
                              hipStream_t stream) {
  const float* x    = (const float*)d_in[0];
  const float* gw   = (const float*)d_in[1];
  const float* bias = (const float*)d_in[2];
  const float* W1   = (const float*)d_in[3];
  const float* W3   = (const float*)d_in[4];
  const float* W2   = (const float*)d_in[5];
  const float* sw1  = (const float*)d_in[6];
  const float* sw3  = (const float*)d_in[7];
  const float* sw2  = (const float*)d_in[8];
  float* out = (float*)d_out;

  char* p = (char*)d_ws;
  auto alloc = [&](size_t bytes) {
    char* r = p; p += (bytes + 255) & ~(size_t)255; return r;
  };
  unsigned short* Xb   = (unsigned short*)alloc((size_t)Tn * Dm * 2);
  unsigned short* W1t  = (unsigned short*)alloc((size_t)En * In * Dm * 2);
  unsigned short* W3t  = (unsigned short*)alloc((size_t)En * In * Dm * 2);
  unsigned short* W2t  = (unsigned short*)alloc((size_t)En * Dm * In * 2);
  unsigned short* sw1b = (unsigned short*)alloc((size_t)SIn * Dm * 2);
  unsigned short* sw3b = (unsigned short*)alloc((size_t)SIn * Dm * 2);
  unsigned short* sw2b = (unsigned short*)alloc((size_t)Dm * SIn * 2);
  unsigned short* act  = (unsigned short*)alloc((size_t)CAP * In * 2);
  unsigned short* actS = (unsigned short*)alloc((size_t)Tn * SIn * 2);
  unsigned short* yR   = (unsigned short*)alloc((size_t)CAP * Dm * 2);
  int*   route_e = (int*)alloc(Tn * 2 * 4);
  float* route_w = (float*)alloc(Tn * 2 * 4);
  int*   counts  = (int*)alloc(256);
  int*   offs    = (int*)alloc(256);
  int*   fill    = (int*)alloc(256);
  int*   ptok    = (int*)alloc(CAP * 4);
  int*   pslot   = (int*)alloc(Tn * 2 * 4);

  // conversions (inputs restored before every call -> must reconvert every call)
  convert_all_kernel<<<dim3(Tn * Dm / 4 / 256, 4), 256, 0, stream>>>(
      x, sw1, sw3, sw2, Xb, sw1b, sw3b, sw2b);
  transpose_all_kernel<<<dim3((Dm / 32) * (In / 32), En, 3), 256, 0, stream>>>(
      W1, W3, W2, W1t, W3t, W2t);

  // routing
  init_kernel<<<(CAP + 255) / 256, 256, 0, stream>>>(counts, ptok);
  router_kernel<<<Tn, 64, 0, stream>>>(x, gw, bias, route_e, route_w, counts);
  offsets_kernel<<<1, 1, 0, stream>>>(counts, offs, fill);
  scatter_kernel<<<Tn * 2 / 256, 256, 0, stream>>>(route_e, fill, ptok, pslot);

  // merged GEMMs
  h_gemm_all<<<RT_H + SH_H, 256, 0, stream>>>(
      Xb, W1t, W3t, sw1b, sw3b, act, actS, ptok, offs);
  o_gemm_all<<<RT_O + SH_O, 256, 0, stream>>>(
      act, actS, W2t, sw2b, yR, out, offs);
  combine_kernel<<<Tn * (Dm / 4) / 256, 256, 0, stream>>>(yR, pslot, route_w, out);
}